// Round 15
// baseline (378.176 us; speedup 1.0000x reference)
//
#include <hip/hip_runtime.h>
#include <hip/hip_bf16.h>

using bf16 = __hip_bfloat16;
typedef __attribute__((ext_vector_type(8))) short short8;   // 8 x bf16 fragment (4 VGPRs)
typedef __attribute__((ext_vector_type(4))) float f32x4;
typedef unsigned long long ull;

static constexpr int SEQ  = 2048;
static constexpr int HID  = 3072;
static constexpr int NH   = 24;
static constexpr int HD   = 128;
static constexpr int QKVN = 9216;

__device__ __forceinline__ f32x4 mfma_16x16x32(short8 a, short8 b, f32x4 c) {
  return __builtin_amdgcn_mfma_f32_16x16x32_bf16(a, b, c, 0, 0, 0);
}

#define GLOAD_LDS16(g, l) __builtin_amdgcn_global_load_lds(                 \
    (const __attribute__((address_space(1))) void*)(g),                    \
    (__attribute__((address_space(3))) void*)(l), 16, 0, 0)

typedef __attribute__((address_space(3))) const unsigned char lds_cchar;

__device__ __forceinline__ unsigned pack_bf16(float lo, float hi) {
  bf16 l = __float2bfloat16(lo), h = __float2bfloat16(hi);
  return (unsigned)*(unsigned short*)&l | ((unsigned)*(unsigned short*)&h << 16);
}

// ---------------- fp32 -> bf16 vectorized convert ----------------
__global__ __launch_bounds__(256)
void cvt_f32_bf16_vec(const float* __restrict__ src, bf16* __restrict__ dst, int n4) {
  int i = blockIdx.x * 256 + threadIdx.x;
  if (i >= n4) return;
  float4 v = ((const float4*)src)[i];
  ushort4 o;
  bf16 t0 = __float2bfloat16(v.x); o.x = *(unsigned short*)&t0;
  bf16 t1 = __float2bfloat16(v.y); o.y = *(unsigned short*)&t1;
  bf16 t2 = __float2bfloat16(v.z); o.z = *(unsigned short*)&t2;
  bf16 t3 = __float2bfloat16(v.w); o.w = *(unsigned short*)&t3;
  ((ushort4*)dst)[i] = o;
}

// ---------------- fp32 (R x C) -> bf16 transposed (C x R), vectorized stores ----------------
__global__ __launch_bounds__(256)
void transpose_cvt64(const float* __restrict__ src, bf16* __restrict__ dst, int R, int C) {
  __shared__ float tile[32][65];
  const int c0 = blockIdx.x * 64, r0 = blockIdx.y * 32;
  const int lc = threadIdx.x & 63, lt = threadIdx.x >> 6;
  #pragma unroll
  for (int i = 0; i < 8; ++i)
    tile[lt + i * 4][lc] = src[(size_t)(r0 + lt + i * 4) * C + c0 + lc];
  __syncthreads();
  const int u = threadIdx.x & 15, dr = threadIdx.x >> 4;
  #pragma unroll
  for (int j = 0; j < 4; ++j) {
    const int cc = dr + j * 16;
    bf16 x0 = __float2bfloat16(tile[u * 2][cc]);
    bf16 x1 = __float2bfloat16(tile[u * 2 + 1][cc]);
    ushort2 o;
    o.x = *(unsigned short*)&x0; o.y = *(unsigned short*)&x1;
    *(ushort2*)&dst[(size_t)(c0 + cc) * R + r0 + u * 2] = o;
  }
}

// ---------------- GEMM1: 256x288, grid EXACTLY 256, 12 waves, 4M x 3N split (r13 win) ----------------
template<int BIAS>
__global__ __launch_bounds__(768, 3)
void gemm12w(const bf16* __restrict__ A, const bf16* __restrict__ BT,
             const float* __restrict__ bias, bf16* __restrict__ Cout,
             int M, int N, int K) {
  __shared__ __align__(16) bf16 Asb[2][256 * 64];
  __shared__ __align__(16) bf16 Bsb[2][288 * 64];

  const int tid  = threadIdx.x;
  const int lane = tid & 63;
  const int wid  = tid >> 6;          // 0..11
  const int wmm  = wid & 3;           // 0..3 -> rows wmm*64..
  const int wnn  = wid >> 2;          // 0..2 -> cols wnn*96..
  const int lr   = lane & 15;
  const int lg   = lane >> 4;

  const int xcd = blockIdx.x & 7;
  const int q   = blockIdx.x >> 3;          // 0..31
  const int bm  = (q & 7) * 256;            // 8 M tiles
  const int bn  = (xcd * 4 + (q >> 3)) * 288;  // 4 N tiles per XCD (B L2-resident)

  const int lrow = lane >> 3;
  const int csrc = ((lane & 7) ^ lrow) * 8;
  const bf16* Abase = A  + (size_t)(bm + lrow) * K + csrc;
  const bf16* Bbase = BT + (size_t)(bn + lrow) * K + csrc;

#define STG12(b, u, i) do {                                                       \
    const int L_ = wid + 12 * (i);                                                \
    if (L_ < 32)      GLOAD_LDS16(Abase + (size_t)(8 * L_) * K + (size_t)(u) * 64,\
                                  &Asb[b][L_ * 512]);                             \
    else if (L_ < 68) GLOAD_LDS16(Bbase + (size_t)(8 * (L_ - 32)) * K + (size_t)(u) * 64, \
                                  &Bsb[b][(L_ - 32) * 512]);                      \
  } while (0)
#define RA12(b, m, kk) (*(const short8*)(&Asb[b][(wmm * 64 + (m) * 16 + lr) * 64 \
                          + ((((kk) * 4 + lg)) ^ (lr & 7)) * 8]))
#define RB12(b, n, kk) (*(const short8*)(&Bsb[b][(wnn * 96 + (n) * 16 + lr) * 64 \
                          + ((((kk) * 4 + lg)) ^ (lr & 7)) * 8]))

  f32x4 acc[4][6] = {};
  const int NT = K >> 6;   // 48

  #pragma unroll
  for (int i = 0; i < 6; ++i) STG12(0, 0, i);

  for (int t = 0; t < NT; ++t) {
    const int c = t & 1, nc = c ^ 1;
    const bool pf = (t + 1) < NT;
    short8 a[4], b[6];

    asm volatile("s_waitcnt vmcnt(0)" ::: "memory");
    __builtin_amdgcn_s_barrier();

    if (pf) {
      STG12(nc, t + 1, 0); STG12(nc, t + 1, 1); STG12(nc, t + 1, 2);
      STG12(nc, t + 1, 3); STG12(nc, t + 1, 4); STG12(nc, t + 1, 5);
    }
    __builtin_amdgcn_sched_barrier(0);

    // kk0
    b[0] = RB12(c, 0, 0); b[1] = RB12(c, 1, 0); b[2] = RB12(c, 2, 0);
    b[3] = RB12(c, 3, 0); b[4] = RB12(c, 4, 0); b[5] = RB12(c, 5, 0);
    a[0] = RA12(c, 0, 0); a[1] = RA12(c, 1, 0); a[2] = RA12(c, 2, 0); a[3] = RA12(c, 3, 0);
    #pragma unroll
    for (int n = 0; n < 6; ++n)
      #pragma unroll
      for (int m = 0; m < 4; ++m) acc[m][n] = mfma_16x16x32(a[m], b[n], acc[m][n]);

    // kk1
    b[0] = RB12(c, 0, 1); b[1] = RB12(c, 1, 1); b[2] = RB12(c, 2, 1);
    b[3] = RB12(c, 3, 1); b[4] = RB12(c, 4, 1); b[5] = RB12(c, 5, 1);
    a[0] = RA12(c, 0, 1); a[1] = RA12(c, 1, 1); a[2] = RA12(c, 2, 1); a[3] = RA12(c, 3, 1);
    #pragma unroll
    for (int n = 0; n < 6; ++n)
      #pragma unroll
      for (int m = 0; m < 4; ++m) acc[m][n] = mfma_16x16x32(a[m], b[n], acc[m][n]);
  }
#undef STG12
#undef RA12
#undef RB12

  const int row0 = bm + wmm * 64 + lg * 4;
  const int col0 = bn + wnn * 96 + lr;
  #pragma unroll
  for (int n = 0; n < 6; ++n) {
    const int col = col0 + n * 16;
    const float bv = BIAS ? bias[col] : 0.0f;
    #pragma unroll
    for (int m = 0; m < 4; ++m)
      #pragma unroll
      for (int r = 0; r < 4; ++r)
        Cout[(size_t)(row0 + m * 16 + r) * N + col] = __float2bfloat16(acc[m][n][r] + bv);
  }
}

// ---------------- GEMM2: 128x96 tile, 4 waves, grid 512 = 2 blocks/CU (r12, proven) ----------------
__global__ __launch_bounds__(256, 2)
void gemm4w(const bf16* __restrict__ A, const bf16* __restrict__ BT,
            float* __restrict__ Cout, int M, int N, int K) {
  __shared__ __align__(16) bf16 Asb[2][128 * 64];
  __shared__ __align__(16) bf16 Bsb[2][96 * 64];

  const int tid  = threadIdx.x;
  const int lane = tid & 63;
  const int wid  = tid >> 6;          // 0..3
  const int wm   = wid >> 1;          // 0..1 -> rows wm*64..
  const int wn   = wid & 1;           // 0..1 -> cols wn*48..
  const int lr   = lane & 15;
  const int lg   = lane >> 4;

  const int xcd = blockIdx.x & 7;
  const int q   = blockIdx.x >> 3;          // 0..63
  const int bm  = (q & 15) * 128;
  const int bn  = (xcd * 4 + (q >> 4)) * 96;

  const int lrow = lane >> 3;
  const int csrc = ((lane & 7) ^ lrow) * 8;
  const bf16* Abase = A  + (size_t)(bm + lrow) * K + csrc;
  const bf16* Bbase = BT + (size_t)(bn + lrow) * K + csrc;

#define STG4(b, u, i) do {                                                        \
    const int L_ = wid + 4 * (i);                                                 \
    if (L_ < 16)      GLOAD_LDS16(Abase + (size_t)(8 * L_) * K + (size_t)(u) * 64,\
                                  &Asb[b][L_ * 512]);                             \
    else if (L_ < 28) GLOAD_LDS16(Bbase + (size_t)(8 * (L_ - 16)) * K + (size_t)(u) * 64, \
                                  &Bsb[b][(L_ - 16) * 512]);                      \
  } while (0)
#define RA4(b, m, kk) (*(const short8*)(&Asb[b][(wm * 64 + (m) * 16 + lr) * 64 \
                          + ((((kk) * 4 + lg)) ^ (lr & 7)) * 8]))
#define RB4(b, n, kk) (*(const short8*)(&Bsb[b][(wn * 48 + (n) * 16 + lr) * 64 \
                          + ((((kk) * 4 + lg)) ^ (lr & 7)) * 8]))

  f32x4 acc[4][3] = {};
  const int NT = K >> 6;   // 48

  #pragma unroll
  for (int i = 0; i < 7; ++i) STG4(0, 0, i);

  for (int t = 0; t < NT; ++t) {
    const int c = t & 1, nc = c ^ 1;
    const bool pf = (t + 1) < NT;
    short8 a[4], b[3];

    asm volatile("s_waitcnt vmcnt(0)" ::: "memory");
    __builtin_amdgcn_s_barrier();

    if (pf) {
      STG4(nc, t + 1, 0); STG4(nc, t + 1, 1); STG4(nc, t + 1, 2); STG4(nc, t + 1, 3);
      STG4(nc, t + 1, 4); STG4(nc, t + 1, 5); STG4(nc, t + 1, 6);
    }
    __builtin_amdgcn_sched_barrier(0);

    b[0] = RB4(c, 0, 0); b[1] = RB4(c, 1, 0); b[2] = RB4(c, 2, 0);
    a[0] = RA4(c, 0, 0); a[1] = RA4(c, 1, 0); a[2] = RA4(c, 2, 0); a[3] = RA4(c, 3, 0);
    #pragma unroll
    for (int n = 0; n < 3; ++n)
      #pragma unroll
      for (int m = 0; m < 4; ++m) acc[m][n] = mfma_16x16x32(a[m], b[n], acc[m][n]);

    b[0] = RB4(c, 0, 1); b[1] = RB4(c, 1, 1); b[2] = RB4(c, 2, 1);
    a[0] = RA4(c, 0, 1); a[1] = RA4(c, 1, 1); a[2] = RA4(c, 2, 1); a[3] = RA4(c, 3, 1);
    #pragma unroll
    for (int n = 0; n < 3; ++n)
      #pragma unroll
      for (int m = 0; m < 4; ++m) acc[m][n] = mfma_16x16x32(a[m], b[n], acc[m][n]);
  }
#undef STG4
#undef RA4
#undef RB4

  const int row0 = bm + wm * 64 + lg * 4;
  const int col0 = bn + wn * 48 + lr;
  #pragma unroll
  for (int n = 0; n < 3; ++n) {
    const int col = col0 + n * 16;
    #pragma unroll
    for (int m = 0; m < 4; ++m)
      #pragma unroll
      for (int r = 0; r < 4; ++r)
        Cout[(size_t)(row0 + m * 16 + r) * N + col] = acc[m][n][r];
  }
}

// ---------------- RMSNorm over q,k head rows (128 elems), one wave per row (r12) ----------------
__global__ __launch_bounds__(256)
void rmsnorm_qk(bf16* __restrict__ qkv, const float* __restrict__ qw,
                const float* __restrict__ kw) {
  const int row  = blockIdx.x * 4 + (threadIdx.x >> 6);
  const int lane = threadIdx.x & 63;
  const int token = row / 48;
  const int rem   = row - token * 48;
  const int which = rem / 24;
  const int head  = rem - which * 24;
  bf16* p = qkv + (size_t)token * QKVN + which * HID + head * HD;
  const float a = __bfloat162float(p[lane * 2]);
  const float b = __bfloat162float(p[lane * 2 + 1]);
  float ss = a * a + b * b;
  #pragma unroll
  for (int mask = 32; mask >= 1; mask >>= 1) ss += __shfl_xor(ss, mask);
  const float inv = rsqrtf(ss * (1.0f / 128.0f) + 1e-6f);
  const float* w = which ? kw : qw;
  p[lane * 2]     = __float2bfloat16(a * inv * w[lane * 2]);
  p[lane * 2 + 1] = __float2bfloat16(b * inv * w[lane * 2 + 1]);
}

// ---------------- flash attention: 2 waves x 32 q-rows (halved K/V read amplification) ----------------
// Block = 2 waves, each owning 32 q-rows as two 16-q halves. K fragment read once
// feeds BOTH halves' QK MFMAs; V tr-read feeds 4 PV MFMAs. Per-CU LDS traffic/tile
// drops 528->~350 KB while total MFMA count is unchanged. Grid stays 768 = 3/CU.
__global__ __launch_bounds__(128)
void attn_kernel(const bf16* __restrict__ qkv, bf16* __restrict__ ctx) {
  const int head = blockIdx.y;
  const int qb   = blockIdx.x;
  const int tid  = threadIdx.x;        // 0..127
  const int lane = tid & 63;
  const int wid  = tid >> 6;           // 0..1
  const int lr   = lane & 15;
  const int lg   = lane >> 4;

  __shared__ __align__(16) unsigned char Ksb[64 * 256];      // 16 KB swizzled
  __shared__ __align__(16) unsigned char Vsb[128 * 128];     // 16 KB subtiled
  __shared__ __align__(16) unsigned short Ps[2][32 * 72];    // 9.2 KB

  const int qrow0 = qb * 64 + wid * 32;
  short8 qf0[4], qf1[4];
  #pragma unroll
  for (int kt = 0; kt < 4; ++kt) {
    qf0[kt] = *(const short8*)(qkv + (size_t)(qrow0 + lr) * QKVN + head * HD + kt * 32 + lg * 8);
    qf1[kt] = *(const short8*)(qkv + (size_t)(qrow0 + 16 + lr) * QKVN + head * HD + kt * 32 + lg * 8);
  }

  f32x4 oacc0[8] = {}, oacc1[8] = {};
  float mrun0 = -1e30f, lsum0 = 0.0f;
  float mrun1 = -1e30f, lsum1 = 0.0f;

  const float scale = 0.088388347648318447f;   // 1/sqrt(128)

  const int stok = tid >> 4;    // 0..7
  const int sdc  = tid & 15;

  short8 kreg[8], vreg[8];
  #pragma unroll
  for (int j = 0; j < 8; ++j) {
    const int tok = stok + j * 8;
    kreg[j] = *(const short8*)(qkv + (size_t)tok * QKVN + HID     + head * HD + sdc * 8);
    vreg[j] = *(const short8*)(qkv + (size_t)tok * QKVN + 2 * HID + head * HD + sdc * 8);
  }

#define TRISSUE(S, dtv) {                                                         \
    lds_cchar* pd_ = vb0 + (dtv) * 2048;                                          \
    asm volatile("ds_read_b64_tr_b16 %0, %1 offset:0"    : "=v"(S##0) : "v"(pd_));\
    asm volatile("ds_read_b64_tr_b16 %0, %1 offset:512"  : "=v"(S##1) : "v"(pd_));\
    asm volatile("ds_read_b64_tr_b16 %0, %1 offset:1024" : "=v"(S##2) : "v"(pd_));\
    asm volatile("ds_read_b64_tr_b16 %0, %1 offset:1536" : "=v"(S##3) : "v"(pd_));}
#define TRMFMA(S, dtv) {                                                          \
    short8 v0_, v1_;                                                              \
    ((ull*)&v0_)[0] = S##0; ((ull*)&v0_)[1] = S##1;                               \
    ((ull*)&v1_)[0] = S##2; ((ull*)&v1_)[1] = S##3;                               \
    oacc0[dtv] = mfma_16x16x32(pa00, v0_, oacc0[dtv]);                            \
    oacc0[dtv] = mfma_16x16x32(pa01, v1_, oacc0[dtv]);                            \
    oacc1[dtv] = mfma_16x16x32(pa10, v0_, oacc1[dtv]);                            \
    oacc1[dtv] = mfma_16x16x32(pa11, v1_, oacc1[dtv]); }
#define TRWAIT4 asm volatile("s_waitcnt lgkmcnt(4)" ::: "memory"); \
                __builtin_amdgcn_sched_barrier(0);

  for (int t = 0; t < SEQ / 64; ++t) {
    __syncthreads();
    #pragma unroll
    for (int j = 0; j < 8; ++j) {
      const int tok = stok + j * 8;
      const int dc  = sdc;
      *(short8*)(Ksb + ((tok * 256 + dc * 16) ^ ((tok & 7) << 4))) = kreg[j];
      const int dg = dc >> 1, h = dc & 1, kg = tok >> 2, kr = tok & 3;
      const int pos = (kg & 8) | ((kg & 1) << 2) | ((kg >> 1) & 3);
      *(short8*)(Vsb + (dg * 16 + pos) * 128 + kr * 32 + h * 16) = vreg[j];
    }
    __syncthreads();

    if (t + 1 < SEQ / 64) {                      // T14 prefetch under compute
      const int kv1 = (t + 1) * 64;
      #pragma unroll
      for (int j = 0; j < 8; ++j) {
        const int tok = kv1 + stok + j * 8;
        kreg[j] = *(const short8*)(qkv + (size_t)tok * QKVN + HID     + head * HD + sdc * 8);
        vreg[j] = *(const short8*)(qkv + (size_t)tok * QKVN + 2 * HID + head * HD + sdc * 8);
      }
      __builtin_amdgcn_sched_barrier(0);
    }

    // S^T = mfma(K, Q) for BOTH halves off one kb read
    f32x4 st0[4], st1[4];
    __builtin_amdgcn_s_setprio(1);
    #pragma unroll
    for (int ct = 0; ct < 4; ++ct) {
      f32x4 a0 = {}, a1 = {};
      #pragma unroll
      for (int kt = 0; kt < 4; ++kt) {
        short8 kb = *(const short8*)(Ksb +
            ((((ct * 16 + lr) * 256) + kt * 64 + lg * 16) ^ ((lr & 7) << 4)));
        a0 = mfma_16x16x32(kb, qf0[kt], a0);
        a1 = mfma_16x16x32(kb, qf1[kt], a1);
      }
      st0[ct] = a0; st1[ct] = a1;
    }
    __builtin_amdgcn_s_setprio(0);

    // in-lane softmax, half 0 (q = lr) then half 1 (q = 16+lr)
#define SOFTMAX_HALF(ST, MR, LS, OACC, ROWB)  {                                   \
    float pm = ST[0][0];                                                          \
    _Pragma("unroll")                                                             \
    for (int ct = 0; ct < 4; ++ct)                                                \
      _Pragma("unroll")                                                           \
      for (int r = 0; r < 4; ++r) pm = fmaxf(pm, ST[ct][r]);                      \
    pm *= scale;                                                                  \
    pm = fmaxf(pm, __shfl_xor(pm, 16));                                           \
    pm = fmaxf(pm, __shfl_xor(pm, 32));                                           \
    if (!__all(pm <= MR + 8.0f)) {                                                \
      const float mnew = fmaxf(MR, pm);                                           \
      const float corr = __expf(MR - mnew);                                       \
      MR = mnew;                                                                  \
      LS *= corr;                                                                 \
      _Pragma("unroll")                                                           \
      for (int r = 0; r < 4; ++r) {                                               \
        const float cr = __shfl(corr, lg * 4 + r);                                \
        _Pragma("unroll")                                                         \
        for (int dt = 0; dt < 8; ++dt) OACC[dt][r] *= cr;                         \
      }                                                                           \
    }                                                                             \
    float ps = 0.0f;                                                              \
    _Pragma("unroll")                                                             \
    for (int ct = 0; ct < 4; ++ct) {                                              \
      const float p0 = __expf(ST[ct][0] * scale - MR);                            \
      const float p1 = __expf(ST[ct][1] * scale - MR);                            \
      const float p2 = __expf(ST[ct][2] * scale - MR);                            \
      const float p3 = __expf(ST[ct][3] * scale - MR);                            \
      ps += (p0 + p1) + (p2 + p3);                                                \
      uint2 w;                                                                    \
      w.x = pack_bf16(p0, p1);                                                    \
      w.y = pack_bf16(p2, p3);                                                    \
      *(uint2*)&Ps[wid][(ROWB + lr) * 72 + ct * 16 + lg * 4] = w;                 \
    }                                                                             \
    LS += ps; }

    SOFTMAX_HALF(st0, mrun0, lsum0, oacc0, 0)
    SOFTMAX_HALF(st1, mrun1, lsum1, oacc1, 16)
#undef SOFTMAX_HALF

    short8 pa00, pa01, pa10, pa11;
    pa00 = *(const short8*)&Ps[wid][lr * 72 + lg * 8];
    pa01 = *(const short8*)&Ps[wid][lr * 72 + 32 + lg * 8];
    pa10 = *(const short8*)&Ps[wid][(16 + lr) * 72 + lg * 8];
    pa11 = *(const short8*)&Ps[wid][(16 + lr) * 72 + 32 + lg * 8];
    __builtin_amdgcn_sched_barrier(0);   // pin pa's 4 ds_reads older than tr-reads (FIFO)

    lds_cchar* vb0 = (lds_cchar*)Vsb + lane * 8;
    ull x0, x1, x2, x3, y0, y1, y2, y3;
    __builtin_amdgcn_s_setprio(1);
    TRISSUE(x, 0)
    TRISSUE(y, 1)
    TRWAIT4  TRMFMA(x, 0)  TRISSUE(x, 2)   // lgkmcnt(4): retires pa(4)+x(4), y in flight
    TRWAIT4  TRMFMA(y, 1)  TRISSUE(y, 3)
    TRWAIT4  TRMFMA(x, 2)  TRISSUE(x, 4)
    TRWAIT4  TRMFMA(y, 3)  TRISSUE(y, 5)
    TRWAIT4  TRMFMA(x, 4)  TRISSUE(x, 6)
    TRWAIT4  TRMFMA(y, 5)  TRISSUE(y, 7)
    TRWAIT4  TRMFMA(x, 6)
    asm volatile("s_waitcnt lgkmcnt(0)" ::: "memory");
    __builtin_amdgcn_sched_barrier(0);
    TRMFMA(y, 7)
    __builtin_amdgcn_s_setprio(0);
  }
#undef TRISSUE
#undef TRMFMA
#undef TRWAIT4

  // epilogue: reduce per-lane partial sums, broadcast to O rows, write both halves
  lsum0 += __shfl_xor(lsum0, 16);
  lsum0 += __shfl_xor(lsum0, 32);
  lsum1 += __shfl_xor(lsum1, 16);
  lsum1 += __shfl_xor(lsum1, 32);
  const float invl0 = 1.0f / lsum0;
  const float invl1 = 1.0f / lsum1;
  #pragma unroll
  for (int r = 0; r < 4; ++r) {
    const float i0 = __shfl(invl0, lg * 4 + r);
    const float i1 = __shfl(invl1, lg * 4 + r);
    const size_t tok0 = qrow0 + lg * 4 + r;
    const size_t tok1 = qrow0 + 16 + lg * 4 + r;
    #pragma unroll
    for (int dt = 0; dt < 8; ++dt) {
      ctx[tok0 * HID + head * HD + dt * 16 + lr] = __float2bfloat16(oacc0[dt][r] * i0);
      ctx[tok1 * HID + head * HD + dt * 16 + lr] = __float2bfloat16(oacc1[dt][r] * i1);
    }
  }
}

extern "C" void kernel_launch(void* const* d_in, const int* in_sizes, int n_in,
                              void* d_out, int out_size, void* d_ws, size_t ws_size,
                              hipStream_t stream) {
  (void)in_sizes; (void)n_in; (void)out_size; (void)ws_size;
  const float* x     = (const float*)d_in[0];
  const float* Wqkv  = (const float*)d_in[1];
  const float* bqkv  = (const float*)d_in[2];
  const float* Wproj = (const float*)d_in[3];
  const float* qw    = (const float*)d_in[4];
  const float* kw    = (const float*)d_in[5];

  char* ws = (char*)d_ws;
  bf16* xb     = (bf16*)ws;                     // 2048x3072 bf16
  bf16* WqkvT  = (bf16*)(ws + 12582912);        // 9216x3072 bf16
  bf16* WprojT = (bf16*)(ws + 69206016);        // 3072x3072 bf16
  bf16* qkv    = (bf16*)(ws + 88080384);        // 2048x9216 bf16
  bf16* ctx    = xb;                            // xb dead after GEMM1

  cvt_f32_bf16_vec<<<(SEQ * HID / 4 + 255) / 256, 256, 0, stream>>>(x, xb, SEQ * HID / 4);
  transpose_cvt64<<<dim3(QKVN / 64, HID / 32), 256, 0, stream>>>(Wqkv, WqkvT, HID, QKVN);
  transpose_cvt64<<<dim3(HID / 64, HID / 32), 256, 0, stream>>>(Wproj, WprojT, HID, HID);

  gemm12w<1><<<256, 768, 0, stream>>>(xb, WqkvT, bqkv, qkv, SEQ, QKVN, HID);

  rmsnorm_qk<<<SEQ * 48 / 4, 256, 0, stream>>>(qkv, qw, kw);

  attn_kernel<<<dim3(SEQ / 64, NH), 128, 0, stream>>>(qkv, ctx);

  gemm4w<<<512, 256, 0, stream>>>(ctx, WprojT, (float*)d_out, SEQ, HID, HID);
}

// Round 16
// 310.548 us; speedup vs baseline: 1.2178x; 1.2178x over previous
//
#include <hip/hip_runtime.h>
#include <hip/hip_bf16.h>

using bf16 = __hip_bfloat16;
typedef __attribute__((ext_vector_type(8))) short short8;   // 8 x bf16 fragment (4 VGPRs)
typedef __attribute__((ext_vector_type(4))) float f32x4;
typedef unsigned long long ull;

static constexpr int SEQ  = 2048;
static constexpr int HID  = 3072;
static constexpr int NH   = 24;
static constexpr int HD   = 128;
static constexpr int QKVN = 9216;

__device__ __forceinline__ f32x4 mfma_16x16x32(short8 a, short8 b, f32x4 c) {
  return __builtin_amdgcn_mfma_f32_16x16x32_bf16(a, b, c, 0, 0, 0);
}

#define GLOAD_LDS16(g, l) __builtin_amdgcn_global_load_lds(                 \
    (const __attribute__((address_space(1))) void*)(g),                    \
    (__attribute__((address_space(3))) void*)(l), 16, 0, 0)

typedef __attribute__((address_space(3))) const unsigned char lds_cchar;

__device__ __forceinline__ unsigned pack_bf16(float lo, float hi) {
  bf16 l = __float2bfloat16(lo), h = __float2bfloat16(hi);
  return (unsigned)*(unsigned short*)&l | ((unsigned)*(unsigned short*)&h << 16);
}

// ---------------- fp32 -> bf16 vectorized convert ----------------
__global__ __launch_bounds__(256)
void cvt_f32_bf16_vec(const float* __restrict__ src, bf16* __restrict__ dst, int n4) {
  int i = blockIdx.x * 256 + threadIdx.x;
  if (i >= n4) return;
  float4 v = ((const float4*)src)[i];
  ushort4 o;
  bf16 t0 = __float2bfloat16(v.x); o.x = *(unsigned short*)&t0;
  bf16 t1 = __float2bfloat16(v.y); o.y = *(unsigned short*)&t1;
  bf16 t2 = __float2bfloat16(v.z); o.z = *(unsigned short*)&t2;
  bf16 t3 = __float2bfloat16(v.w); o.w = *(unsigned short*)&t3;
  ((ushort4*)dst)[i] = o;
}

// ---------------- fp32 (R x C) -> bf16 transposed (C x R), vectorized stores ----------------
__global__ __launch_bounds__(256)
void transpose_cvt64(const float* __restrict__ src, bf16* __restrict__ dst, int R, int C) {
  __shared__ float tile[32][65];
  const int c0 = blockIdx.x * 64, r0 = blockIdx.y * 32;
  const int lc = threadIdx.x & 63, lt = threadIdx.x >> 6;
  #pragma unroll
  for (int i = 0; i < 8; ++i)
    tile[lt + i * 4][lc] = src[(size_t)(r0 + lt + i * 4) * C + c0 + lc];
  __syncthreads();
  const int u = threadIdx.x & 15, dr = threadIdx.x >> 4;
  #pragma unroll
  for (int j = 0; j < 4; ++j) {
    const int cc = dr + j * 16;
    bf16 x0 = __float2bfloat16(tile[u * 2][cc]);
    bf16 x1 = __float2bfloat16(tile[u * 2 + 1][cc]);
    ushort2 o;
    o.x = *(unsigned short*)&x0; o.y = *(unsigned short*)&x1;
    *(ushort2*)&dst[(size_t)(c0 + cc) * R + r0 + u * 2] = o;
  }
}

// ---------------- GEMM1: 256x288, grid EXACTLY 256, 12 waves, 4M x 3N split (r13 win) ----------------
template<int BIAS>
__global__ __launch_bounds__(768, 3)
void gemm12w(const bf16* __restrict__ A, const bf16* __restrict__ BT,
             const float* __restrict__ bias, bf16* __restrict__ Cout,
             int M, int N, int K) {
  __shared__ __align__(16) bf16 Asb[2][256 * 64];
  __shared__ __align__(16) bf16 Bsb[2][288 * 64];

  const int tid  = threadIdx.x;
  const int lane = tid & 63;
  const int wid  = tid >> 6;          // 0..11
  const int wmm  = wid & 3;           // 0..3 -> rows wmm*64..
  const int wnn  = wid >> 2;          // 0..2 -> cols wnn*96..
  const int lr   = lane & 15;
  const int lg   = lane >> 4;

  const int xcd = blockIdx.x & 7;
  const int q   = blockIdx.x >> 3;          // 0..31
  const int bm  = (q & 7) * 256;            // 8 M tiles
  const int bn  = (xcd * 4 + (q >> 3)) * 288;  // 4 N tiles per XCD (B L2-resident)

  const int lrow = lane >> 3;
  const int csrc = ((lane & 7) ^ lrow) * 8;
  const bf16* Abase = A  + (size_t)(bm + lrow) * K + csrc;
  const bf16* Bbase = BT + (size_t)(bn + lrow) * K + csrc;

#define STG12(b, u, i) do {                                                       \
    const int L_ = wid + 12 * (i);                                                \
    if (L_ < 32)      GLOAD_LDS16(Abase + (size_t)(8 * L_) * K + (size_t)(u) * 64,\
                                  &Asb[b][L_ * 512]);                             \
    else if (L_ < 68) GLOAD_LDS16(Bbase + (size_t)(8 * (L_ - 32)) * K + (size_t)(u) * 64, \
                                  &Bsb[b][(L_ - 32) * 512]);                      \
  } while (0)
#define RA12(b, m, kk) (*(const short8*)(&Asb[b][(wmm * 64 + (m) * 16 + lr) * 64 \
                          + ((((kk) * 4 + lg)) ^ (lr & 7)) * 8]))
#define RB12(b, n, kk) (*(const short8*)(&Bsb[b][(wnn * 96 + (n) * 16 + lr) * 64 \
                          + ((((kk) * 4 + lg)) ^ (lr & 7)) * 8]))

  f32x4 acc[4][6] = {};
  const int NT = K >> 6;   // 48

  #pragma unroll
  for (int i = 0; i < 6; ++i) STG12(0, 0, i);

  for (int t = 0; t < NT; ++t) {
    const int c = t & 1, nc = c ^ 1;
    const bool pf = (t + 1) < NT;
    short8 a[4], b[6];

    asm volatile("s_waitcnt vmcnt(0)" ::: "memory");
    __builtin_amdgcn_s_barrier();

    if (pf) {
      STG12(nc, t + 1, 0); STG12(nc, t + 1, 1); STG12(nc, t + 1, 2);
      STG12(nc, t + 1, 3); STG12(nc, t + 1, 4); STG12(nc, t + 1, 5);
    }
    __builtin_amdgcn_sched_barrier(0);

    // kk0
    b[0] = RB12(c, 0, 0); b[1] = RB12(c, 1, 0); b[2] = RB12(c, 2, 0);
    b[3] = RB12(c, 3, 0); b[4] = RB12(c, 4, 0); b[5] = RB12(c, 5, 0);
    a[0] = RA12(c, 0, 0); a[1] = RA12(c, 1, 0); a[2] = RA12(c, 2, 0); a[3] = RA12(c, 3, 0);
    #pragma unroll
    for (int n = 0; n < 6; ++n)
      #pragma unroll
      for (int m = 0; m < 4; ++m) acc[m][n] = mfma_16x16x32(a[m], b[n], acc[m][n]);

    // kk1
    b[0] = RB12(c, 0, 1); b[1] = RB12(c, 1, 1); b[2] = RB12(c, 2, 1);
    b[3] = RB12(c, 3, 1); b[4] = RB12(c, 4, 1); b[5] = RB12(c, 5, 1);
    a[0] = RA12(c, 0, 1); a[1] = RA12(c, 1, 1); a[2] = RA12(c, 2, 1); a[3] = RA12(c, 3, 1);
    #pragma unroll
    for (int n = 0; n < 6; ++n)
      #pragma unroll
      for (int m = 0; m < 4; ++m) acc[m][n] = mfma_16x16x32(a[m], b[n], acc[m][n]);
  }
#undef STG12
#undef RA12
#undef RB12

  const int row0 = bm + wmm * 64 + lg * 4;
  const int col0 = bn + wnn * 96 + lr;
  #pragma unroll
  for (int n = 0; n < 6; ++n) {
    const int col = col0 + n * 16;
    const float bv = BIAS ? bias[col] : 0.0f;
    #pragma unroll
    for (int m = 0; m < 4; ++m)
      #pragma unroll
      for (int r = 0; r < 4; ++r)
        Cout[(size_t)(row0 + m * 16 + r) * N + col] = __float2bfloat16(acc[m][n][r] + bv);
  }
}

// ---------------- GEMM2: 128x96 tile, 4 waves, grid 512 = 2 blocks/CU (r12, proven) ----------------
__global__ __launch_bounds__(256, 2)
void gemm4w(const bf16* __restrict__ A, const bf16* __restrict__ BT,
            float* __restrict__ Cout, int M, int N, int K) {
  __shared__ __align__(16) bf16 Asb[2][128 * 64];
  __shared__ __align__(16) bf16 Bsb[2][96 * 64];

  const int tid  = threadIdx.x;
  const int lane = tid & 63;
  const int wid  = tid >> 6;          // 0..3
  const int wm   = wid >> 1;          // 0..1 -> rows wm*64..
  const int wn   = wid & 1;           // 0..1 -> cols wn*48..
  const int lr   = lane & 15;
  const int lg   = lane >> 4;

  const int xcd = blockIdx.x & 7;
  const int q   = blockIdx.x >> 3;          // 0..63
  const int bm  = (q & 15) * 128;
  const int bn  = (xcd * 4 + (q >> 4)) * 96;

  const int lrow = lane >> 3;
  const int csrc = ((lane & 7) ^ lrow) * 8;
  const bf16* Abase = A  + (size_t)(bm + lrow) * K + csrc;
  const bf16* Bbase = BT + (size_t)(bn + lrow) * K + csrc;

#define STG4(b, u, i) do {                                                        \
    const int L_ = wid + 4 * (i);                                                 \
    if (L_ < 16)      GLOAD_LDS16(Abase + (size_t)(8 * L_) * K + (size_t)(u) * 64,\
                                  &Asb[b][L_ * 512]);                             \
    else if (L_ < 28) GLOAD_LDS16(Bbase + (size_t)(8 * (L_ - 16)) * K + (size_t)(u) * 64, \
                                  &Bsb[b][(L_ - 16) * 512]);                      \
  } while (0)
#define RA4(b, m, kk) (*(const short8*)(&Asb[b][(wm * 64 + (m) * 16 + lr) * 64 \
                          + ((((kk) * 4 + lg)) ^ (lr & 7)) * 8]))
#define RB4(b, n, kk) (*(const short8*)(&Bsb[b][(wn * 48 + (n) * 16 + lr) * 64 \
                          + ((((kk) * 4 + lg)) ^ (lr & 7)) * 8]))

  f32x4 acc[4][3] = {};
  const int NT = K >> 6;   // 48

  #pragma unroll
  for (int i = 0; i < 7; ++i) STG4(0, 0, i);

  for (int t = 0; t < NT; ++t) {
    const int c = t & 1, nc = c ^ 1;
    const bool pf = (t + 1) < NT;
    short8 a[4], b[3];

    asm volatile("s_waitcnt vmcnt(0)" ::: "memory");
    __builtin_amdgcn_s_barrier();

    if (pf) {
      STG4(nc, t + 1, 0); STG4(nc, t + 1, 1); STG4(nc, t + 1, 2); STG4(nc, t + 1, 3);
      STG4(nc, t + 1, 4); STG4(nc, t + 1, 5); STG4(nc, t + 1, 6);
    }
    __builtin_amdgcn_sched_barrier(0);

    b[0] = RB4(c, 0, 0); b[1] = RB4(c, 1, 0); b[2] = RB4(c, 2, 0);
    a[0] = RA4(c, 0, 0); a[1] = RA4(c, 1, 0); a[2] = RA4(c, 2, 0); a[3] = RA4(c, 3, 0);
    #pragma unroll
    for (int n = 0; n < 3; ++n)
      #pragma unroll
      for (int m = 0; m < 4; ++m) acc[m][n] = mfma_16x16x32(a[m], b[n], acc[m][n]);

    b[0] = RB4(c, 0, 1); b[1] = RB4(c, 1, 1); b[2] = RB4(c, 2, 1);
    a[0] = RA4(c, 0, 1); a[1] = RA4(c, 1, 1); a[2] = RA4(c, 2, 1); a[3] = RA4(c, 3, 1);
    #pragma unroll
    for (int n = 0; n < 3; ++n)
      #pragma unroll
      for (int m = 0; m < 4; ++m) acc[m][n] = mfma_16x16x32(a[m], b[n], acc[m][n]);
  }
#undef STG4
#undef RA4
#undef RB4

  const int row0 = bm + wm * 64 + lg * 4;
  const int col0 = bn + wn * 48 + lr;
  #pragma unroll
  for (int n = 0; n < 3; ++n) {
    const int col = col0 + n * 16;
    #pragma unroll
    for (int m = 0; m < 4; ++m)
      #pragma unroll
      for (int r = 0; r < 4; ++r)
        Cout[(size_t)(row0 + m * 16 + r) * N + col] = acc[m][n][r];
  }
}

// ---------------- RMSNorm over q,k head rows (128 elems), one wave per row (r12) ----------------
__global__ __launch_bounds__(256)
void rmsnorm_qk(bf16* __restrict__ qkv, const float* __restrict__ qw,
                const float* __restrict__ kw) {
  const int row  = blockIdx.x * 4 + (threadIdx.x >> 6);
  const int lane = threadIdx.x & 63;
  const int token = row / 48;
  const int rem   = row - token * 48;
  const int which = rem / 24;
  const int head  = rem - which * 24;
  bf16* p = qkv + (size_t)token * QKVN + which * HID + head * HD;
  const float a = __bfloat162float(p[lane * 2]);
  const float b = __bfloat162float(p[lane * 2 + 1]);
  float ss = a * a + b * b;
  #pragma unroll
  for (int mask = 32; mask >= 1; mask >>= 1) ss += __shfl_xor(ss, mask);
  const float inv = rsqrtf(ss * (1.0f / 128.0f) + 1e-6f);
  const float* w = which ? kw : qw;
  p[lane * 2]     = __float2bfloat16(a * inv * w[lane * 2]);
  p[lane * 2 + 1] = __float2bfloat16(b * inv * w[lane * 2 + 1]);
}

// ---------------- flash attention (r12-proven): swapped QK^T, in-lane softmax, pipelined PV ----------------
__global__ __launch_bounds__(256, 3)
void attn_kernel(const bf16* __restrict__ qkv, bf16* __restrict__ ctx) {
  const int head = blockIdx.y;
  const int qb   = blockIdx.x;
  const int tid  = threadIdx.x;
  const int lane = tid & 63;
  const int wid  = tid >> 6;
  const int lr   = lane & 15;
  const int lg   = lane >> 4;

  __shared__ __align__(16) unsigned char Ksb[64 * 256];
  __shared__ __align__(16) unsigned char Vsb[128 * 128];
  __shared__ __align__(16) unsigned short Ps[4][16 * 72];

  const int qrow0 = qb * 64 + wid * 16;
  short8 qf[4];
  #pragma unroll
  for (int kt = 0; kt < 4; ++kt)
    qf[kt] = *(const short8*)(qkv + (size_t)(qrow0 + lr) * QKVN + head * HD + kt * 32 + lg * 8);

  f32x4 oacc[8] = {};
  float mrun = -1e30f, lsum = 0.0f;   // per-lane stats for q-row = lr

  const float scale = 0.088388347648318447f;   // 1/sqrt(128)

  const int stok = tid >> 4;
  const int sdc  = tid & 15;

  short8 kreg[4], vreg[4];
  #pragma unroll
  for (int j = 0; j < 4; ++j) {
    const int tok = stok + (j & 1) * 16 + (j >> 1) * 32;
    kreg[j] = *(const short8*)(qkv + (size_t)tok * QKVN + HID     + head * HD + sdc * 8);
    vreg[j] = *(const short8*)(qkv + (size_t)tok * QKVN + 2 * HID + head * HD + sdc * 8);
  }

#define TRISSUE(S, dtv) {                                                         \
    lds_cchar* pd_ = vb0 + (dtv) * 2048;                                          \
    asm volatile("ds_read_b64_tr_b16 %0, %1 offset:0"    : "=v"(S##0) : "v"(pd_));\
    asm volatile("ds_read_b64_tr_b16 %0, %1 offset:512"  : "=v"(S##1) : "v"(pd_));\
    asm volatile("ds_read_b64_tr_b16 %0, %1 offset:1024" : "=v"(S##2) : "v"(pd_));\
    asm volatile("ds_read_b64_tr_b16 %0, %1 offset:1536" : "=v"(S##3) : "v"(pd_));}
#define TRMFMA(S, dtv) {                                                          \
    short8 v0_, v1_;                                                              \
    ((ull*)&v0_)[0] = S##0; ((ull*)&v0_)[1] = S##1;                               \
    ((ull*)&v1_)[0] = S##2; ((ull*)&v1_)[1] = S##3;                               \
    oacc[dtv] = mfma_16x16x32(pa[0], v0_, oacc[dtv]);                             \
    oacc[dtv] = mfma_16x16x32(pa[1], v1_, oacc[dtv]); }
#define TRWAIT4 asm volatile("s_waitcnt lgkmcnt(4)" ::: "memory"); \
                __builtin_amdgcn_sched_barrier(0);

  for (int t = 0; t < SEQ / 64; ++t) {
    __syncthreads();
    #pragma unroll
    for (int j = 0; j < 4; ++j) {
      const int tok = stok + (j & 1) * 16 + (j >> 1) * 32;
      const int dc  = sdc;
      *(short8*)(Ksb + ((tok * 256 + dc * 16) ^ ((tok & 7) << 4))) = kreg[j];
      const int dg = dc >> 1, h = dc & 1, kg = tok >> 2, kr = tok & 3;
      const int pos = (kg & 8) | ((kg & 1) << 2) | ((kg >> 1) & 3);
      *(short8*)(Vsb + (dg * 16 + pos) * 128 + kr * 32 + h * 16) = vreg[j];
    }
    __syncthreads();

    if (t + 1 < SEQ / 64) {
      const int kv1 = (t + 1) * 64;
      #pragma unroll
      for (int j = 0; j < 4; ++j) {
        const int tok = kv1 + stok + (j & 1) * 16 + (j >> 1) * 32;
        kreg[j] = *(const short8*)(qkv + (size_t)tok * QKVN + HID     + head * HD + sdc * 8);
        vreg[j] = *(const short8*)(qkv + (size_t)tok * QKVN + 2 * HID + head * HD + sdc * 8);
      }
      __builtin_amdgcn_sched_barrier(0);
    }

    // S^T = mfma(K, Q): st[ct][r] = S[q=lr][key=ct*16+lg*4+r]
    f32x4 st[4];
    __builtin_amdgcn_s_setprio(1);
    #pragma unroll
    for (int ct = 0; ct < 4; ++ct) {
      f32x4 a = {};
      #pragma unroll
      for (int kt = 0; kt < 4; ++kt) {
        short8 kb = *(const short8*)(Ksb +
            ((((ct * 16 + lr) * 256) + kt * 64 + lg * 16) ^ ((lr & 7) << 4)));
        a = mfma_16x16x32(kb, qf[kt], a);    // swapped operands -> S^T
      }
      st[ct] = a;
    }
    __builtin_amdgcn_s_setprio(0);

    // in-lane softmax for q = lr over this lane's 16 keys
    float pm = st[0][0];
    #pragma unroll
    for (int ct = 0; ct < 4; ++ct)
      #pragma unroll
      for (int r = 0; r < 4; ++r) pm = fmaxf(pm, st[ct][r]);
    pm *= scale;
    pm = fmaxf(pm, __shfl_xor(pm, 16));
    pm = fmaxf(pm, __shfl_xor(pm, 32));

    // T13 defer-max
    if (!__all(pm <= mrun + 8.0f)) {
      const float mnew = fmaxf(mrun, pm);
      const float corr = __expf(mrun - mnew);
      mrun = mnew;
      lsum *= corr;
      #pragma unroll
      for (int r = 0; r < 4; ++r) {
        const float cr = __shfl(corr, lg * 4 + r);
        #pragma unroll
        for (int dt = 0; dt < 8; ++dt) oacc[dt][r] *= cr;
      }
    }

    float ps = 0.0f;
    #pragma unroll
    for (int ct = 0; ct < 4; ++ct) {
      const float p0 = __expf(st[ct][0] * scale - mrun);
      const float p1 = __expf(st[ct][1] * scale - mrun);
      const float p2 = __expf(st[ct][2] * scale - mrun);
      const float p3 = __expf(st[ct][3] * scale - mrun);
      ps += (p0 + p1) + (p2 + p3);
      uint2 w;
      w.x = pack_bf16(p0, p1);
      w.y = pack_bf16(p2, p3);
      *(uint2*)&Ps[wid][lr * 72 + ct * 16 + lg * 4] = w;
    }
    lsum += ps;

    short8 pa[2];
    pa[0] = *(const short8*)&Ps[wid][lr * 72 + lg * 8];
    pa[1] = *(const short8*)&Ps[wid][lr * 72 + 32 + lg * 8];
    __builtin_amdgcn_sched_barrier(0);   // pin pa's ds_reads older than tr-reads (FIFO)

    lds_cchar* vb0 = (lds_cchar*)Vsb + lane * 8;
    ull x0, x1, x2, x3, y0, y1, y2, y3;
    __builtin_amdgcn_s_setprio(1);
    TRISSUE(x, 0)
    TRISSUE(y, 1)
    TRWAIT4  TRMFMA(x, 0)  TRISSUE(x, 2)
    TRWAIT4  TRMFMA(y, 1)  TRISSUE(y, 3)
    TRWAIT4  TRMFMA(x, 2)  TRISSUE(x, 4)
    TRWAIT4  TRMFMA(y, 3)  TRISSUE(y, 5)
    TRWAIT4  TRMFMA(x, 4)  TRISSUE(x, 6)
    TRWAIT4  TRMFMA(y, 5)  TRISSUE(y, 7)
    TRWAIT4  TRMFMA(x, 6)
    asm volatile("s_waitcnt lgkmcnt(0)" ::: "memory");
    __builtin_amdgcn_sched_barrier(0);
    TRMFMA(y, 7)
    __builtin_amdgcn_s_setprio(0);
  }
#undef TRISSUE
#undef TRMFMA
#undef TRWAIT4

  // epilogue: reduce per-lane partial sums (q=lr), broadcast to O rows (q=lg*4+r)
  lsum += __shfl_xor(lsum, 16);
  lsum += __shfl_xor(lsum, 32);
  const float invl = 1.0f / lsum;
  #pragma unroll
  for (int r = 0; r < 4; ++r) {
    const float inv = __shfl(invl, lg * 4 + r);
    const size_t tok = qrow0 + lg * 4 + r;
    #pragma unroll
    for (int dt = 0; dt < 8; ++dt)
      ctx[tok * HID + head * HD + dt * 16 + lr] = __float2bfloat16(oacc[dt][r] * inv);
  }
}

extern "C" void kernel_launch(void* const* d_in, const int* in_sizes, int n_in,
                              void* d_out, int out_size, void* d_ws, size_t ws_size,
                              hipStream_t stream) {
  (void)in_sizes; (void)n_in; (void)out_size; (void)ws_size;
  const float* x     = (const float*)d_in[0];
  const float* Wqkv  = (const float*)d_in[1];
  const float* bqkv  = (const float*)d_in[2];
  const float* Wproj = (const float*)d_in[3];
  const float* qw    = (const float*)d_in[4];
  const float* kw    = (const float*)d_in[5];

  char* ws = (char*)d_ws;
  bf16* xb     = (bf16*)ws;                     // 2048x3072 bf16
  bf16* WqkvT  = (bf16*)(ws + 12582912);        // 9216x3072 bf16
  bf16* WprojT = (bf16*)(ws + 69206016);        // 3072x3072 bf16
  bf16* qkv    = (bf16*)(ws + 88080384);        // 2048x9216 bf16
  bf16* ctx    = xb;                            // xb dead after GEMM1

  cvt_f32_bf16_vec<<<(SEQ * HID / 4 + 255) / 256, 256, 0, stream>>>(x, xb, SEQ * HID / 4);
  transpose_cvt64<<<dim3(QKVN / 64, HID / 32), 256, 0, stream>>>(Wqkv, WqkvT, HID, QKVN);
  transpose_cvt64<<<dim3(HID / 64, HID / 32), 256, 0, stream>>>(Wproj, WprojT, HID, HID);

  gemm12w<1><<<256, 768, 0, stream>>>(xb, WqkvT, bqkv, qkv, SEQ, QKVN, HID);

  rmsnorm_qk<<<SEQ * 48 / 4, 256, 0, stream>>>(qkv, qw, kw);

  attn_kernel<<<dim3(SEQ / 64, NH), 256, 0, stream>>>(qkv, ctx);

  gemm4w<<<512, 256, 0, stream>>>(ctx, WprojT, (float*)d_out, SEQ, HID, HID);
}